// Round 1
// 122.994 us; speedup vs baseline: 1.2226x; 1.2226x over previous
//
#include <hip/hip_runtime.h>
#include <math.h>

// Problem constants: B=4, N=256, C=512, H=8, Dh=64
#define BB 4
#define NN 256
#define CC 512
#define HH 8
#define DH 64

typedef __attribute__((ext_vector_type(8))) short bf16x8;
typedef __attribute__((ext_vector_type(4))) float f32x4;

__device__ inline unsigned short f2bf(float f) {
  unsigned u = __float_as_uint(f);
  u += 0x7FFFu + ((u >> 16) & 1u);  // round-to-nearest-even
  return (unsigned short)(u >> 16);
}
__device__ inline float bf2f(unsigned short s) {
  return __uint_as_float((unsigned)s << 16);
}

// ---------------------------------------------------------------------------
// Fused fp32 -> (hi, lo) bf16 split for all three inputs in ONE launch.
// Segments (blocks): x = 512, w_qkv = 768, w_proj = 256  -> grid 1536.
// ---------------------------------------------------------------------------
__global__ __launch_bounds__(256) void cvt_hilo3(
    const float* __restrict__ in0, unsigned short* __restrict__ h0,
    unsigned short* __restrict__ l0, const float* __restrict__ in1,
    unsigned short* __restrict__ h1, unsigned short* __restrict__ l1,
    const float* __restrict__ in2, unsigned short* __restrict__ h2,
    unsigned short* __restrict__ l2) {
  int b = blockIdx.x;
  const float* in;
  unsigned short *h, *l;
  if (b < 512) {
    in = in0; h = h0; l = l0;
  } else if (b < 1280) {
    in = in1; h = h1; l = l1; b -= 512;
  } else {
    in = in2; h = h2; l = l2; b -= 1280;
  }
  int i = (b * 256 + threadIdx.x) * 4;
  float4 f = *(const float4*)(in + i);
  float fa[4] = {f.x, f.y, f.z, f.w};
  ushort4 hv, lv;
  unsigned short* hp = (unsigned short*)&hv;
  unsigned short* lp = (unsigned short*)&lv;
#pragma unroll
  for (int j = 0; j < 4; j++) {
    unsigned short hb = f2bf(fa[j]);
    hp[j] = hb;
    lp[j] = f2bf(fa[j] - bf2f(hb));
  }
  *(ushort4*)(h + i) = hv;
  *(ushort4*)(l + i) = lv;
}

// ---------------------------------------------------------------------------
// MFMA GEMM, bf16 hi/lo split (3 products): C = A * B^T (+bias).
// v2: 64x64 tile (4x parallelism vs 128x128 -> gemm1 384 blocks, gemm2 128),
// BK=64, register-prefetch of next K-slab during MFMA phase (T14).
// 256 thr = 4 waves; wave -> 32x32 (2x2 mfma 16x16x32).
// LDS rows padded to 72 shorts (144B): frag b128 reads conflict-free
// (16*l mod 128 distinct over 8-lane phases); staging stores conflict-free.
// M,N multiples of 64; K multiple of 64.
// ---------------------------------------------------------------------------
template <bool BIAS>
__global__ __launch_bounds__(256, 2) void gemm_mfma(
    const unsigned short* __restrict__ Ah, const unsigned short* __restrict__ Al,
    const unsigned short* __restrict__ Bh, const unsigned short* __restrict__ Bl,
    const float* __restrict__ bias, float* __restrict__ C, int M, int N,
    int K) {
  __shared__ unsigned short sAh[64][72], sAl[64][72];
  __shared__ unsigned short sBh[64][72], sBl[64][72];
  const int t = threadIdx.x;
  const int lane = t & 63;
  const int w = t >> 6;
  const int bm = blockIdx.y * 64;
  const int bn = blockIdx.x * 64;
  const int wr = (w >> 1) * 32;  // wave row offset in tile
  const int wc = (w & 1) * 32;   // wave col offset
  const int quad = lane >> 4;
  const int l16 = lane & 15;

  // staging: 512 slots of 8 shorts per array; thread t handles slots t, t+256
  const int r0 = t >> 3;        // 0..31
  const int r1 = r0 + 32;       // 32..63
  const int c8 = (t & 7) * 8;   // 0..56

  const size_t a0 = (size_t)(bm + r0) * K + c8;
  const size_t a1 = (size_t)(bm + r1) * K + c8;
  const size_t b0 = (size_t)(bn + r0) * K + c8;
  const size_t b1 = (size_t)(bn + r1) * K + c8;

  f32x4 acc[2][2];
#pragma unroll
  for (int i = 0; i < 2; i++)
#pragma unroll
    for (int j = 0; j < 2; j++) {
      acc[i][j][0] = 0.f;
      acc[i][j][1] = 0.f;
      acc[i][j][2] = 0.f;
      acc[i][j][3] = 0.f;
    }

  uint4 pa0, pa1, pa2, pa3, pb0, pb1, pb2, pb3;
#define GLOADS(K0)                          \
  pa0 = *(const uint4*)(Ah + a0 + (K0));    \
  pa1 = *(const uint4*)(Ah + a1 + (K0));    \
  pa2 = *(const uint4*)(Al + a0 + (K0));    \
  pa3 = *(const uint4*)(Al + a1 + (K0));    \
  pb0 = *(const uint4*)(Bh + b0 + (K0));    \
  pb1 = *(const uint4*)(Bh + b1 + (K0));    \
  pb2 = *(const uint4*)(Bl + b0 + (K0));    \
  pb3 = *(const uint4*)(Bl + b1 + (K0));

  GLOADS(0)

  for (int k0 = 0; k0 < K; k0 += 64) {
    __syncthreads();  // previous tile's LDS reads complete
    *(uint4*)&sAh[r0][c8] = pa0;
    *(uint4*)&sAh[r1][c8] = pa1;
    *(uint4*)&sAl[r0][c8] = pa2;
    *(uint4*)&sAl[r1][c8] = pa3;
    *(uint4*)&sBh[r0][c8] = pb0;
    *(uint4*)&sBh[r1][c8] = pb1;
    *(uint4*)&sBl[r0][c8] = pb2;
    *(uint4*)&sBl[r1][c8] = pb3;
    __syncthreads();
    if (k0 + 64 < K) {
      GLOADS(k0 + 64)  // hidden under the MFMA phase below
    }
#pragma unroll
    for (int kk = 0; kk < 2; kk++) {
      const int kc = kk * 32 + quad * 8;
      bf16x8 ah[2], al[2], bh[2], bl[2];
#pragma unroll
      for (int i = 0; i < 2; i++) {
        ah[i] = *(const bf16x8*)&sAh[wr + i * 16 + l16][kc];
        al[i] = *(const bf16x8*)&sAl[wr + i * 16 + l16][kc];
        bh[i] = *(const bf16x8*)&sBh[wc + i * 16 + l16][kc];
        bl[i] = *(const bf16x8*)&sBl[wc + i * 16 + l16][kc];
      }
#pragma unroll
      for (int i = 0; i < 2; i++)
#pragma unroll
        for (int j = 0; j < 2; j++) {
          acc[i][j] = __builtin_amdgcn_mfma_f32_16x16x32_bf16(
              ah[i], bh[j], acc[i][j], 0, 0, 0);
          acc[i][j] = __builtin_amdgcn_mfma_f32_16x16x32_bf16(
              ah[i], bl[j], acc[i][j], 0, 0, 0);
          acc[i][j] = __builtin_amdgcn_mfma_f32_16x16x32_bf16(
              al[i], bh[j], acc[i][j], 0, 0, 0);
        }
    }
  }
#undef GLOADS

  // epilogue: C/D layout col=lane&15, row=quad*4+reg (verified m89/m91)
#pragma unroll
  for (int i = 0; i < 2; i++)
#pragma unroll
    for (int j = 0; j < 2; j++) {
      int n = bn + wc + j * 16 + l16;
      float bv = BIAS ? bias[n] : 0.f;
#pragma unroll
      for (int r = 0; r < 4; r++) {
        int m = bm + wr + i * 16 + quad * 4 + r;
        C[(size_t)m * N + n] = acc[i][j][r] + bv;
      }
    }
}

// ---------------------------------------------------------------------------
// Fused Fourier attention. qkv row (b*N+n): q at [h*64], k at [512+h*64],
// v at [1024+h*64]. Grid (16,H,B); 512 thr = 8 waves, 2 queries/wave.
// v3 changes:
//  - register prefetch of next K/V tile during compute (T14): global-load
//    latency hidden under the ~5us score+AV phase instead of sitting between
//    the two barriers.
//  - sin via v_sin(cR*d) with cR = R/(2pi) hoisted (one fewer VALU mul per
//    sinc eval than __sinf(R*d); identical hardware sin path).
//  - VtT XOR swizzle [d][r ^ (d&60)]: transpose scalar stores go 8-way ->
//    ~2-way bank conflict; AV b128 reads stay <=2-way (free).
// ---------------------------------------------------------------------------
__global__ __launch_bounds__(512, 4) void fourier_attn(
    const float* __restrict__ qkv, const float* __restrict__ paramR,
    unsigned short* __restrict__ aoh, unsigned short* __restrict__ aol) {
  __shared__ float Kt[64][68];    // Kt[key j][d], padded
  __shared__ float VtT[64][68];   // VtT[d][key j ^ (d&60)], swizzled
  __shared__ float Qs[16][DH];    // staged queries
  __shared__ float A4[8][64][2];  // [wave][key j][q]

  const int t = threadIdx.x;
  const int lane = t & 63;
  const int wv = t >> 6;  // 0..7
  const int qc = blockIdx.x;
  const int h = blockIdx.y;
  const int b = blockIdx.z;
  const float R = paramR[0];
  const float cR = R * 0.15915494309189535f;  // R / (2*pi)

  const float* base = qkv + (size_t)b * NN * (3 * CC) + h * DH;

  if (t < 256) {
    int r = t >> 4;
    int c4 = (t & 15) << 2;
    *(float4*)&Qs[r][c4] =
        *(const float4*)(base + (size_t)(qc * 16 + r) * (3 * CC) + c4);
  }

  const int qi0 = wv * 2, qi1 = wv * 2 + 1;
  float Sp[2] = {0.f, 0.f};
  float acc[2] = {0.f, 0.f};

  // prefetch registers for one K/V tile (2 float4 each)
  float4 pk[2], pv[2];
#define LOADT(JT)                                                   \
  _Pragma("unroll") for (int u0 = 0; u0 < 2; u0++) {                \
    int u = t + 512 * u0;                                           \
    int r_ = u >> 4;                                                \
    int c4_ = (u & 15) << 2;                                        \
    const float* row_ = base + (size_t)((JT) * 64 + r_) * (3 * CC); \
    pk[u0] = *(const float4*)(row_ + CC + c4_);                     \
    pv[u0] = *(const float4*)(row_ + 2 * CC + c4_);                 \
  }

  LOADT(0)

  for (int jt = 0; jt < 4; jt++) {
    __syncthreads();  // previous tile's LDS reads (and Qs stage) complete
    // store prefetched K (row-major) and V (transposed, swizzled)
#pragma unroll
    for (int u0 = 0; u0 < 2; u0++) {
      int u = t + 512 * u0;
      int r = u >> 4;          // key row
      int c4 = (u & 15) << 2;  // dim
      *(float4*)&Kt[r][c4] = pk[u0];
      int rs = r ^ c4;  // c4 == (c4+i)&60 for i<4  -> one swizzled col
      float4 vv = pv[u0];
      VtT[c4 + 0][rs] = vv.x;
      VtT[c4 + 1][rs] = vv.y;
      VtT[c4 + 2][rs] = vv.z;
      VtT[c4 + 3][rs] = vv.w;
    }
    __syncthreads();
    if (jt < 3) {
      LOADT(jt + 1)  // hidden under score+AV compute below
    }

    // ---- score phase: lane = key
    float nm[2][2] = {{1.f, 1.f}, {1.f, 1.f}};
    float dn[2][2] = {{1.f, 1.f}, {1.f, 1.f}};
#pragma unroll
    for (int d4 = 0; d4 < 16; d4++) {
      const int p = d4 & 1;
      float4 k4 = *(const float4*)&Kt[lane][4 * d4];
      float4 qa = *(const float4*)&Qs[qi0][4 * d4];
      float4 qb = *(const float4*)&Qs[qi1][4 * d4];
      float ka[4] = {k4.x, k4.y, k4.z, k4.w};
      float q0a[4] = {qa.x, qa.y, qa.z, qa.w};
      float q1a[4] = {qb.x, qb.y, qb.z, qb.w};
#pragma unroll
      for (int j = 0; j < 4; j++) {
        float d0 = q0a[j] - ka[j] + 1e-30f;
        float d1 = q1a[j] - ka[j] + 1e-30f;
        nm[0][p] *= __builtin_amdgcn_sinf(cR * d0);
        dn[0][p] *= d0;
        nm[1][p] *= __builtin_amdgcn_sinf(cR * d1);
        dn[1][p] *= d1;
      }
    }
#pragma unroll
    for (int q = 0; q < 2; q++) {
      float sc = (nm[q][0] * nm[q][1]) / (dn[q][0] * dn[q][1]);
      float s2 = sc * sc;
      float a4 = s2 * s2;
      Sp[q] += a4;
      A4[wv][lane][q] = a4;  // same-wave RAW with AV phase below
    }

    // ---- AV phase: lane = dim; 4 keys per iteration
#pragma unroll
    for (int j4 = 0; j4 < 16; j4++) {
      float4 v4 = *(const float4*)&VtT[lane][(4 * j4) ^ (lane & 60)];
      float4 a01 = *(const float4*)&A4[wv][4 * j4 + 0][0];  // keys j,j+1
      float4 a23 = *(const float4*)&A4[wv][4 * j4 + 2][0];  // keys j+2,j+3
      acc[0] = fmaf(a01.x, v4.x, acc[0]);
      acc[1] = fmaf(a01.y, v4.x, acc[1]);
      acc[0] = fmaf(a01.z, v4.y, acc[0]);
      acc[1] = fmaf(a01.w, v4.y, acc[1]);
      acc[0] = fmaf(a23.x, v4.z, acc[0]);
      acc[1] = fmaf(a23.y, v4.z, acc[1]);
      acc[0] = fmaf(a23.z, v4.w, acc[0]);
      acc[1] = fmaf(a23.w, v4.w, acc[1]);
    }
  }
#undef LOADT

  // ---- finalize: reduce Sp, normalize, store hi/lo bf16
#pragma unroll
  for (int q = 0; q < 2; q++) {
    float s = Sp[q];
#pragma unroll
    for (int off = 32; off > 0; off >>= 1) s += __shfl_xor(s, off, 64);
    float o = acc[q] / (s + 1e-6f);
    int n = qc * 16 + wv * 2 + q;
    size_t idx = (size_t)(b * NN + n) * CC + h * DH + lane;
    unsigned short oh = f2bf(o);
    aoh[idx] = oh;
    aol[idx] = f2bf(o - bf2f(oh));
  }
}

// ---------------------------------------------------------------------------
extern "C" void kernel_launch(void* const* d_in, const int* in_sizes, int n_in,
                              void* d_out, int out_size, void* d_ws,
                              size_t ws_size, hipStream_t stream) {
  const float* x = (const float*)d_in[0];       // (B,N,C)
  const float* w_qkv = (const float*)d_in[1];   // (3C, C)
  const float* w_proj = (const float*)d_in[2];  // (C, C)
  const float* b_proj = (const float*)d_in[3];  // (C,)
  const float* paramR = (const float*)d_in[4];  // (1,)
  float* outp = (float*)d_out;                  // (B,N,C)

  const int nX = BB * NN * CC;  // 524288
  const int nWq = 3 * CC * CC;  // 786432
  const int nWp = CC * CC;      // 262144

  // ws layout (all 16B-aligned)
  unsigned short* xh = (unsigned short*)d_ws;
  unsigned short* xl = xh + nX;
  unsigned short* wqh = xl + nX;
  unsigned short* wql = wqh + nWq;
  unsigned short* wph = wql + nWq;
  unsigned short* wpl = wph + nWp;
  unsigned short* aoh = wpl + nWp;
  unsigned short* aol = aoh + nX;
  float* qkv_ws = (float*)(aol + nX);  // 1024*1536 fp32

  // 1) hi/lo conversions (single fused launch: 512 + 768 + 256 blocks)
  cvt_hilo3<<<1536, 256, 0, stream>>>(x, xh, xl, w_qkv, wqh, wql, w_proj, wph,
                                      wpl);

  // 2) qkv = x @ w_qkv^T : M=1024, N=1536, K=512  (24x16 = 384 blocks)
  gemm_mfma<false><<<dim3(3 * CC / 64, BB * NN / 64), 256, 0, stream>>>(
      xh, xl, wqh, wql, nullptr, qkv_ws, BB * NN, 3 * CC, CC);

  // 3) fused fourier attention -> hi/lo bf16 (B*N, C)
  fourier_attn<<<dim3(NN / 16, HH, BB), 512, 0, stream>>>(qkv_ws, paramR, aoh,
                                                          aol);

  // 4) out = attn @ w_proj^T + b_proj : M=1024, N=512, K=512 (8x16 = 128 blk)
  gemm_mfma<true><<<dim3(CC / 64, BB * NN / 64), 256, 0, stream>>>(
      aoh, aol, wph, wpl, b_proj, outp, BB * NN, CC, CC);
}